// Round 1
// baseline (465.651 us; speedup 1.0000x reference)
//
#include <hip/hip_runtime.h>
#include <hip/hip_bf16.h>

// SwitchMoE: N=16384 tokens, D=512, F=2048, E=8, top-1 routing, capacity=N.
// Sparse formulation: each token goes through exactly ONE expert's FFN
// (gate column e is one-hot-masked), so FFN work is N*(2*D*F)*2 = 68.7 GFLOP
// instead of the reference's dense 8x. Router kept in fp32 (argmax tie
// safety); FFN in bf16 MFMA (16x16x32) with fp32 accumulate.
//
// ws layout (~118 MB): counts/denom/offs | top1/topval/pos/perm |
//   xg bf16[N][D] (expert-gathered) | w1t bf16[E][F][D] (B^T) |
//   w2t bf16[E][D][F] (B^T) | hb bf16[N][F]

typedef unsigned short u16;
typedef unsigned int u32;
typedef __bf16 bf16x8 __attribute__((ext_vector_type(8)));
typedef u16 u16x8 __attribute__((ext_vector_type(8)));
typedef float f32x4 __attribute__((ext_vector_type(4)));

#define N_TOK 16384
#define DIM   512
#define FDIM  2048
#define NEXP  8

__device__ inline u16 f2bf(float f) {
    u32 u = __float_as_uint(f);
    u = (u + 0x7FFF + ((u >> 16) & 1)) >> 16;  // RNE
    return (u16)u;
}

__device__ inline void gload16(const u16* g, u16* l) {
    // async global->LDS, 16B per lane. LDS dest must be wave-uniform base + lane*16.
    __builtin_amdgcn_global_load_lds(
        (const __attribute__((address_space(1))) u32*)g,
        (__attribute__((address_space(3))) u32*)l, 16, 0, 0);
}

// ---------------- Router: logits fp32, argmax, denom, per-expert position ----
__global__ __launch_bounds__(128) void k_router(
    const float* __restrict__ x, const float* __restrict__ Wg,
    int* __restrict__ top1, float* __restrict__ topval,
    int* __restrict__ pos, int* __restrict__ counts, float* __restrict__ denom) {
    __shared__ float xs[16][DIM + 1];
    __shared__ float wgs[NEXP][DIM + 1];
    __shared__ float lg[16][NEXP];
    const int tid = threadIdx.x;
    const int tok0 = blockIdx.x * 16;
    for (int i = tid; i < NEXP * DIM / 4; i += 128) {
        int e = i >> 7, d4 = i & 127;
        float4 v = ((const float4*)Wg)[i];
        int d = d4 * 4;
        wgs[e][d] = v.x; wgs[e][d + 1] = v.y; wgs[e][d + 2] = v.z; wgs[e][d + 3] = v.w;
    }
    for (int i = tid; i < 16 * DIM / 4; i += 128) {
        int r = i >> 7, d4 = i & 127;
        float4 v = ((const float4*)(x + (size_t)(tok0 + r) * DIM))[d4];
        int d = d4 * 4;
        xs[r][d] = v.x; xs[r][d + 1] = v.y; xs[r][d + 2] = v.z; xs[r][d + 3] = v.w;
    }
    __syncthreads();
    {
        int t = tid >> 3, e = tid & 7;
        float acc = 0.f;
        for (int d = 0; d < DIM; ++d) acc += xs[t][d] * wgs[e][d];
        lg[t][e] = acc;
    }
    __syncthreads();
    if (tid < 16) {
        int n = tok0 + tid;
        float best = lg[tid][0];
        int be = 0;
        for (int e = 1; e < NEXP; ++e) {
            float v = lg[tid][e];
            if (v > best) { best = v; be = e; }  // strict > keeps first index (matches jnp.argmax)
        }
        top1[n] = be;
        topval[n] = best;
        pos[n] = atomicAdd(&counts[be], 1);
        atomicAdd(&denom[be], best);
    }
}

__global__ void k_prefix(const int* __restrict__ counts, int* __restrict__ offs) {
    if (threadIdx.x == 0) {
        int s = 0;
        for (int e = 0; e < NEXP; ++e) { offs[e] = s; s += counts[e]; }
        offs[NEXP] = s;
    }
}

// ---------------- Gather x rows into expert-contiguous bf16 ------------------
__global__ __launch_bounds__(256) void k_gather(
    const float* __restrict__ x, const int* __restrict__ top1,
    const int* __restrict__ pos, const int* __restrict__ offs,
    int* __restrict__ perm, u16* __restrict__ xg) {
    const int wid = threadIdx.x >> 6, lane = threadIdx.x & 63;
    const int n = blockIdx.x * 4 + wid;
    const int e = top1[n];
    const int dst = offs[e] + pos[n];
    if (lane == 0) perm[dst] = n;
    const float4* src = (const float4*)(x + (size_t)n * DIM);
    float4 a = src[lane * 2], b = src[lane * 2 + 1];
    u16x8 v;
    v[0] = f2bf(a.x); v[1] = f2bf(a.y); v[2] = f2bf(a.z); v[3] = f2bf(a.w);
    v[4] = f2bf(b.x); v[5] = f2bf(b.y); v[6] = f2bf(b.z); v[7] = f2bf(b.w);
    *(u16x8*)(xg + (size_t)dst * DIM + lane * 8) = v;
}

// ---------------- Transpose + fp32->bf16: dst[c*R + r] = src[r*C + c] --------
__global__ __launch_bounds__(256) void k_transpose_cvt(
    const float* __restrict__ src, u16* __restrict__ dst, int R, int C) {
    __shared__ float tile[32][33];
    const int e = blockIdx.z;
    src += (size_t)e * R * C;
    dst += (size_t)e * R * C;
    const int c0 = blockIdx.x * 32, r0 = blockIdx.y * 32;
    const int tr = threadIdx.x >> 5, tc = threadIdx.x & 31;
    for (int i = 0; i < 4; ++i) {
        int r = tr + i * 8;
        tile[r][tc] = src[(size_t)(r0 + r) * C + c0 + tc];
    }
    __syncthreads();
    for (int i = 0; i < 4; ++i) {
        int r = tr + i * 8;
        dst[(size_t)(c0 + r) * R + r0 + tc] = f2bf(tile[tc][r]);
    }
}

// ---------------- Grouped GEMM1: hb = relu(xg @ W1 + b1), per expert ---------
// A: xg rows [off_e + m][K=512], B^T: w1t[e] = [F][512]. Tile 128x128xBK64.
__global__ __launch_bounds__(256) void k_ffn1(
    const u16* __restrict__ xg, const u16* __restrict__ w1t,
    const float* __restrict__ b1, const int* __restrict__ counts,
    const int* __restrict__ offs, u16* __restrict__ hb) {
    const int bx = blockIdx.x;
    const int e = bx >> 11;
    const int rem = bx & 2047;
    const int mt = rem & 127, nt = rem >> 7;
    const int cnt = counts[e];
    if (mt * 128 >= cnt) return;
    const int off = offs[e];
    __shared__ u16 as[128 * 64];
    __shared__ u16 bs[128 * 64];
    const u16* B = w1t + (size_t)e * FDIM * DIM;
    const int tid = threadIdx.x;
    const int lane = tid & 63, wid = tid >> 6;
    const int wr = wid >> 1, wc = wid & 1;
    const int q = lane >> 4, l15 = lane & 15;
    f32x4 acc[4][4];
    for (int i = 0; i < 4; ++i)
        for (int j = 0; j < 4; ++j) acc[i][j] = f32x4{0.f, 0.f, 0.f, 0.f};

    for (int k0 = 0; k0 < DIM; k0 += 64) {
        for (int it = 0; it < 4; ++it) {
            int chunk = it * 256 + tid;
            int row = chunk >> 3, c = chunk & 7;
            int gcol = c ^ (row & 7);  // XOR swizzle: conflict-free ds_read_b128
            int ga = off + mt * 128 + row;
            if (ga > N_TOK - 1) ga = N_TOK - 1;
            gload16(xg + (size_t)ga * DIM + k0 + gcol * 8, as + chunk * 8);
            int gb = nt * 128 + row;
            gload16(B + (size_t)gb * DIM + k0 + gcol * 8, bs + chunk * 8);
        }
        __syncthreads();
        for (int ks = 0; ks < 64; ks += 32) {
            bf16x8 af[4], bfr[4];
            for (int mi = 0; mi < 4; ++mi) {
                int m = wr * 64 + mi * 16 + l15;
                int cc = ((ks >> 3) + q) ^ (m & 7);
                af[mi] = *(const bf16x8*)(as + m * 64 + cc * 8);
            }
            for (int ni = 0; ni < 4; ++ni) {
                int n = wc * 64 + ni * 16 + l15;
                int cc = ((ks >> 3) + q) ^ (n & 7);
                bfr[ni] = *(const bf16x8*)(bs + n * 64 + cc * 8);
            }
            for (int mi = 0; mi < 4; ++mi)
                for (int ni = 0; ni < 4; ++ni)
                    acc[mi][ni] = __builtin_amdgcn_mfma_f32_16x16x32_bf16(
                        af[mi], bfr[ni], acc[mi][ni], 0, 0, 0);
        }
        __syncthreads();
    }
    const float* b1e = b1 + e * FDIM + nt * 128;
    float bcol[4];
    for (int ni = 0; ni < 4; ++ni) bcol[ni] = b1e[wc * 64 + ni * 16 + l15];
    for (int mi = 0; mi < 4; ++mi) {
        for (int r = 0; r < 4; ++r) {
            int mrow = mt * 128 + wr * 64 + mi * 16 + q * 4 + r;
            if (mrow >= cnt) continue;
            size_t base = (size_t)(off + mrow) * FDIM + nt * 128;
            for (int ni = 0; ni < 4; ++ni) {
                float v = acc[mi][ni][r] + bcol[ni];
                v = v > 0.f ? v : 0.f;
                hb[base + wc * 64 + ni * 16 + l15] = f2bf(v);
            }
        }
    }
}

// ---------------- Grouped GEMM2: out[tok] = gate * (hb @ W2 + b2) ------------
// A: hb rows [off_e + m][K=2048], B^T: w2t[e] = [512][2048]. nt in 0..3.
__global__ __launch_bounds__(256) void k_ffn2(
    const u16* __restrict__ hb, const u16* __restrict__ w2t,
    const float* __restrict__ b2, const int* __restrict__ counts,
    const int* __restrict__ offs, const int* __restrict__ perm,
    const float* __restrict__ topval, const float* __restrict__ denom,
    float* __restrict__ out) {
    const int bx = blockIdx.x;
    const int e = bx >> 9;
    const int rem = bx & 511;
    const int mt = rem & 127, nt = rem >> 7;
    const int cnt = counts[e];
    if (mt * 128 >= cnt) return;
    const int off = offs[e];
    const float scale = 16384.0f / (denom[e] + 1e-6f);
    __shared__ u16 as[128 * 64];
    __shared__ u16 bs[128 * 64];
    const u16* B = w2t + (size_t)e * DIM * FDIM;
    const int tid = threadIdx.x;
    const int lane = tid & 63, wid = tid >> 6;
    const int wr = wid >> 1, wc = wid & 1;
    const int q = lane >> 4, l15 = lane & 15;
    f32x4 acc[4][4];
    for (int i = 0; i < 4; ++i)
        for (int j = 0; j < 4; ++j) acc[i][j] = f32x4{0.f, 0.f, 0.f, 0.f};

    for (int k0 = 0; k0 < FDIM; k0 += 64) {
        for (int it = 0; it < 4; ++it) {
            int chunk = it * 256 + tid;
            int row = chunk >> 3, c = chunk & 7;
            int gcol = c ^ (row & 7);
            int ga = off + mt * 128 + row;
            if (ga > N_TOK - 1) ga = N_TOK - 1;
            gload16(hb + (size_t)ga * FDIM + k0 + gcol * 8, as + chunk * 8);
            int gb = nt * 128 + row;
            gload16(B + (size_t)gb * FDIM + k0 + gcol * 8, bs + chunk * 8);
        }
        __syncthreads();
        for (int ks = 0; ks < 64; ks += 32) {
            bf16x8 af[4], bfr[4];
            for (int mi = 0; mi < 4; ++mi) {
                int m = wr * 64 + mi * 16 + l15;
                int cc = ((ks >> 3) + q) ^ (m & 7);
                af[mi] = *(const bf16x8*)(as + m * 64 + cc * 8);
            }
            for (int ni = 0; ni < 4; ++ni) {
                int n = wc * 64 + ni * 16 + l15;
                int cc = ((ks >> 3) + q) ^ (n & 7);
                bfr[ni] = *(const bf16x8*)(bs + n * 64 + cc * 8);
            }
            for (int mi = 0; mi < 4; ++mi)
                for (int ni = 0; ni < 4; ++ni)
                    acc[mi][ni] = __builtin_amdgcn_mfma_f32_16x16x32_bf16(
                        af[mi], bfr[ni], acc[mi][ni], 0, 0, 0);
        }
        __syncthreads();
    }
    float bcol[4];
    for (int ni = 0; ni < 4; ++ni) bcol[ni] = b2[e * DIM + nt * 128 + wc * 64 + ni * 16 + l15];
    for (int mi = 0; mi < 4; ++mi) {
        for (int r = 0; r < 4; ++r) {
            int mrow = mt * 128 + wr * 64 + mi * 16 + q * 4 + r;
            if (mrow >= cnt) continue;
            int tok = perm[off + mrow];
            float g = topval[tok] * scale;
            size_t base = (size_t)tok * DIM + nt * 128;
            for (int ni = 0; ni < 4; ++ni) {
                float v = acc[mi][ni][r] + bcol[ni];
                out[base + wc * 64 + ni * 16 + l15] = g * v;
            }
        }
    }
}

extern "C" void kernel_launch(void* const* d_in, const int* in_sizes, int n_in,
                              void* d_out, int out_size, void* d_ws, size_t ws_size,
                              hipStream_t stream) {
    const float* x  = (const float*)d_in[0];
    const float* Wg = (const float*)d_in[1];
    const float* W1 = (const float*)d_in[2];
    const float* b1 = (const float*)d_in[3];
    const float* W2 = (const float*)d_in[4];
    const float* b2 = (const float*)d_in[5];
    float* out = (float*)d_out;

    char* W = (char*)d_ws;
    int*   counts = (int*)W;               // 8 ints
    float* denom  = (float*)(W + 64);      // 8 floats
    int*   offs   = (int*)(W + 128);       // 9 ints
    int*   top1   = (int*)(W + 256);
    float* topval = (float*)(W + 256 + 65536);
    int*   pos    = (int*)(W + 256 + 131072);
    int*   perm   = (int*)(W + 256 + 196608);
    u16*   xg     = (u16*)(W + 262400);                     // N*D bf16 = 16 MB
    u16*   w1t    = xg  + (size_t)N_TOK * DIM;              // E*F*D bf16 = 16 MB
    u16*   w2t    = w1t + (size_t)NEXP * FDIM * DIM;        // E*D*F bf16 = 16 MB
    u16*   hb     = w2t + (size_t)NEXP * DIM * FDIM;        // N*F bf16 = 64 MB

    hipMemsetAsync(W, 0, 128, stream);  // counts + denom
    k_router<<<N_TOK / 16, 128, 0, stream>>>(x, Wg, top1, topval, pos, counts, denom);
    k_prefix<<<1, 1, 0, stream>>>(counts, offs);
    k_gather<<<N_TOK / 4, 256, 0, stream>>>(x, top1, pos, offs, perm, xg);
    k_transpose_cvt<<<dim3(FDIM / 32, DIM / 32, NEXP), 256, 0, stream>>>(W1, w1t, DIM, FDIM);
    k_transpose_cvt<<<dim3(DIM / 32, FDIM / 32, NEXP), 256, 0, stream>>>(W2, w2t, FDIM, DIM);
    k_ffn1<<<NEXP * 128 * 16, 256, 0, stream>>>(xg, w1t, b1, counts, offs, hb);
    k_ffn2<<<NEXP * 128 * 4, 256, 0, stream>>>(hb, w2t, b2, counts, offs, perm, topval, denom, out);
}

// Round 2
// 359.945 us; speedup vs baseline: 1.2937x; 1.2937x over previous
//
#include <hip/hip_runtime.h>
#include <hip/hip_bf16.h>

// SwitchMoE: N=16384 tokens, D=512, F=2048, E=8, top-1 routing, capacity=N.
// Sparse formulation: each token goes through exactly ONE expert's FFN
// (gate column e is one-hot-masked), so FFN work is N*(2*D*F)*2 = 68.7 GFLOP
// instead of the reference's dense 8x. Router kept in fp32 (argmax tie
// safety); FFN in bf16 MFMA (16x16x32) with fp32 accumulate.
//
// R2: router rewritten wave-per-token (was 126.8us @ 1.9% VALUBusy; target ~6us).
//
// ws layout (~118 MB): counts/denom/offs | top1/topval/pos/perm |
//   xg bf16[N][D] (expert-gathered) | w1t bf16[E][F][D] (B^T) |
//   w2t bf16[E][D][F] (B^T) | hb bf16[N][F]

typedef unsigned short u16;
typedef unsigned int u32;
typedef __bf16 bf16x8 __attribute__((ext_vector_type(8)));
typedef u16 u16x8 __attribute__((ext_vector_type(8)));
typedef float f32x4 __attribute__((ext_vector_type(4)));

#define N_TOK 16384
#define DIM   512
#define FDIM  2048
#define NEXP  8

__device__ inline u16 f2bf(float f) {
    u32 u = __float_as_uint(f);
    u = (u + 0x7FFF + ((u >> 16) & 1)) >> 16;  // RNE
    return (u16)u;
}

__device__ inline void gload16(const u16* g, u16* l) {
    // async global->LDS, 16B per lane. LDS dest must be wave-uniform base + lane*16.
    __builtin_amdgcn_global_load_lds(
        (const __attribute__((address_space(1))) u32*)g,
        (__attribute__((address_space(3))) u32*)l, 16, 0, 0);
}

// ---------------- Router: wave-per-token fp32 logits + argmax + block-agg ----
// Block 256 = 4 waves; each wave processes 8 tokens -> 32 tokens/block.
// Lane l covers d in [4l,4l+4) and [256+4l,256+4l+4): conflict-free b128 LDS
// reads of Wg and coalesced global x reads. Per-block LDS histogram collapses
// the counts/denom atomics to <=8 global atomicAdds per block.
__global__ __launch_bounds__(256) void k_router(
    const float* __restrict__ x, const float* __restrict__ Wg,
    int* __restrict__ top1, float* __restrict__ topval,
    int* __restrict__ pos, int* __restrict__ counts, float* __restrict__ denom) {
    __shared__ float4 wgs4[NEXP * 128];   // 16 KB, Wg[e][d] as float4
    __shared__ int   lcnt[NEXP];
    __shared__ float lden[NEXP];
    __shared__ int   lbase[NEXP];
    __shared__ int   ltok_e[32];
    __shared__ int   ltok_r[32];
    const int tid = threadIdx.x;
    const int lane = tid & 63, wv = tid >> 6;
    for (int i = tid; i < NEXP * 128; i += 256) wgs4[i] = ((const float4*)Wg)[i];
    if (tid < NEXP) { lcnt[tid] = 0; lden[tid] = 0.f; }
    __syncthreads();
    const int tok0 = blockIdx.x * 32;
    for (int tt = 0; tt < 8; ++tt) {
        const int tloc = wv * 8 + tt;
        const int n = tok0 + tloc;
        const float4* xr = (const float4*)(x + (size_t)n * DIM);
        float4 a = xr[lane], b = xr[64 + lane];
        float p[NEXP];
#pragma unroll
        for (int e = 0; e < NEXP; ++e) {
            float4 wa = wgs4[e * 128 + lane], wb = wgs4[e * 128 + 64 + lane];
            p[e] = a.x * wa.x + a.y * wa.y + a.z * wa.z + a.w * wa.w
                 + b.x * wb.x + b.y * wb.y + b.z * wb.z + b.w * wb.w;
        }
#pragma unroll
        for (int e = 0; e < NEXP; ++e)
#pragma unroll
            for (int m = 32; m >= 1; m >>= 1)
                p[e] += __shfl_xor(p[e], m, 64);
        if (lane == 0) {
            float best = p[0]; int be = 0;
#pragma unroll
            for (int e = 1; e < NEXP; ++e)
                if (p[e] > best) { best = p[e]; be = e; }  // strict >: first idx wins (jnp.argmax)
            top1[n] = be;
            topval[n] = best;
            ltok_e[tloc] = be;
            ltok_r[tloc] = atomicAdd(&lcnt[be], 1);
            atomicAdd(&lden[be], best);
        }
    }
    __syncthreads();
    if (tid < NEXP) {
        int c = lcnt[tid];
        lbase[tid] = c ? atomicAdd(&counts[tid], c) : 0;
        float dsum = lden[tid];
        if (dsum != 0.f) atomicAdd(&denom[tid], dsum);
    }
    __syncthreads();
    if (tid < 32) {
        int n = tok0 + tid;
        pos[n] = lbase[ltok_e[tid]] + ltok_r[tid];
    }
}

__global__ void k_prefix(const int* __restrict__ counts, int* __restrict__ offs) {
    if (threadIdx.x == 0) {
        int s = 0;
        for (int e = 0; e < NEXP; ++e) { offs[e] = s; s += counts[e]; }
        offs[NEXP] = s;
    }
}

// ---------------- Gather x rows into expert-contiguous bf16 ------------------
__global__ __launch_bounds__(256) void k_gather(
    const float* __restrict__ x, const int* __restrict__ top1,
    const int* __restrict__ pos, const int* __restrict__ offs,
    int* __restrict__ perm, u16* __restrict__ xg) {
    const int wid = threadIdx.x >> 6, lane = threadIdx.x & 63;
    const int n = blockIdx.x * 4 + wid;
    const int e = top1[n];
    const int dst = offs[e] + pos[n];
    if (lane == 0) perm[dst] = n;
    const float4* src = (const float4*)(x + (size_t)n * DIM);
    float4 a = src[lane * 2], b = src[lane * 2 + 1];
    u16x8 v;
    v[0] = f2bf(a.x); v[1] = f2bf(a.y); v[2] = f2bf(a.z); v[3] = f2bf(a.w);
    v[4] = f2bf(b.x); v[5] = f2bf(b.y); v[6] = f2bf(b.z); v[7] = f2bf(b.w);
    *(u16x8*)(xg + (size_t)dst * DIM + lane * 8) = v;
}

// ---------------- Transpose + fp32->bf16: dst[c*R + r] = src[r*C + c] --------
__global__ __launch_bounds__(256) void k_transpose_cvt(
    const float* __restrict__ src, u16* __restrict__ dst, int R, int C) {
    __shared__ float tile[32][33];
    const int e = blockIdx.z;
    src += (size_t)e * R * C;
    dst += (size_t)e * R * C;
    const int c0 = blockIdx.x * 32, r0 = blockIdx.y * 32;
    const int tr = threadIdx.x >> 5, tc = threadIdx.x & 31;
    for (int i = 0; i < 4; ++i) {
        int r = tr + i * 8;
        tile[r][tc] = src[(size_t)(r0 + r) * C + c0 + tc];
    }
    __syncthreads();
    for (int i = 0; i < 4; ++i) {
        int r = tr + i * 8;
        dst[(size_t)(c0 + r) * R + r0 + tc] = f2bf(tile[tc][r]);
    }
}

// ---------------- Grouped GEMM1: hb = relu(xg @ W1 + b1), per expert ---------
// A: xg rows [off_e + m][K=512], B^T: w1t[e] = [F][512]. Tile 128x128xBK64.
__global__ __launch_bounds__(256) void k_ffn1(
    const u16* __restrict__ xg, const u16* __restrict__ w1t,
    const float* __restrict__ b1, const int* __restrict__ counts,
    const int* __restrict__ offs, u16* __restrict__ hb) {
    const int bx = blockIdx.x;
    const int e = bx >> 11;
    const int rem = bx & 2047;
    const int mt = rem & 127, nt = rem >> 7;
    const int cnt = counts[e];
    if (mt * 128 >= cnt) return;
    const int off = offs[e];
    __shared__ u16 as[128 * 64];
    __shared__ u16 bs[128 * 64];
    const u16* B = w1t + (size_t)e * FDIM * DIM;
    const int tid = threadIdx.x;
    const int lane = tid & 63, wid = tid >> 6;
    const int wr = wid >> 1, wc = wid & 1;
    const int q = lane >> 4, l15 = lane & 15;
    f32x4 acc[4][4];
    for (int i = 0; i < 4; ++i)
        for (int j = 0; j < 4; ++j) acc[i][j] = f32x4{0.f, 0.f, 0.f, 0.f};

    for (int k0 = 0; k0 < DIM; k0 += 64) {
        for (int it = 0; it < 4; ++it) {
            int chunk = it * 256 + tid;
            int row = chunk >> 3, c = chunk & 7;
            int gcol = c ^ (row & 7);  // XOR swizzle: conflict-free ds_read_b128
            int ga = off + mt * 128 + row;
            if (ga > N_TOK - 1) ga = N_TOK - 1;
            gload16(xg + (size_t)ga * DIM + k0 + gcol * 8, as + chunk * 8);
            int gb = nt * 128 + row;
            gload16(B + (size_t)gb * DIM + k0 + gcol * 8, bs + chunk * 8);
        }
        __syncthreads();
        for (int ks = 0; ks < 64; ks += 32) {
            bf16x8 af[4], bfr[4];
            for (int mi = 0; mi < 4; ++mi) {
                int m = wr * 64 + mi * 16 + l15;
                int cc = ((ks >> 3) + q) ^ (m & 7);
                af[mi] = *(const bf16x8*)(as + m * 64 + cc * 8);
            }
            for (int ni = 0; ni < 4; ++ni) {
                int n = wc * 64 + ni * 16 + l15;
                int cc = ((ks >> 3) + q) ^ (n & 7);
                bfr[ni] = *(const bf16x8*)(bs + n * 64 + cc * 8);
            }
            for (int mi = 0; mi < 4; ++mi)
                for (int ni = 0; ni < 4; ++ni)
                    acc[mi][ni] = __builtin_amdgcn_mfma_f32_16x16x32_bf16(
                        af[mi], bfr[ni], acc[mi][ni], 0, 0, 0);
        }
        __syncthreads();
    }
    const float* b1e = b1 + e * FDIM + nt * 128;
    float bcol[4];
    for (int ni = 0; ni < 4; ++ni) bcol[ni] = b1e[wc * 64 + ni * 16 + l15];
    for (int mi = 0; mi < 4; ++mi) {
        for (int r = 0; r < 4; ++r) {
            int mrow = mt * 128 + wr * 64 + mi * 16 + q * 4 + r;
            if (mrow >= cnt) continue;
            size_t base = (size_t)(off + mrow) * FDIM + nt * 128;
            for (int ni = 0; ni < 4; ++ni) {
                float v = acc[mi][ni][r] + bcol[ni];
                v = v > 0.f ? v : 0.f;
                hb[base + wc * 64 + ni * 16 + l15] = f2bf(v);
            }
        }
    }
}

// ---------------- Grouped GEMM2: out[tok] = gate * (hb @ W2 + b2) ------------
// A: hb rows [off_e + m][K=2048], B^T: w2t[e] = [512][2048]. nt in 0..3.
__global__ __launch_bounds__(256) void k_ffn2(
    const u16* __restrict__ hb, const u16* __restrict__ w2t,
    const float* __restrict__ b2, const int* __restrict__ counts,
    const int* __restrict__ offs, const int* __restrict__ perm,
    const float* __restrict__ topval, const float* __restrict__ denom,
    float* __restrict__ out) {
    const int bx = blockIdx.x;
    const int e = bx >> 9;
    const int rem = bx & 511;
    const int mt = rem & 127, nt = rem >> 7;
    const int cnt = counts[e];
    if (mt * 128 >= cnt) return;
    const int off = offs[e];
    const float scale = 16384.0f / (denom[e] + 1e-6f);
    __shared__ u16 as[128 * 64];
    __shared__ u16 bs[128 * 64];
    const u16* B = w2t + (size_t)e * DIM * FDIM;
    const int tid = threadIdx.x;
    const int lane = tid & 63, wid = tid >> 6;
    const int wr = wid >> 1, wc = wid & 1;
    const int q = lane >> 4, l15 = lane & 15;
    f32x4 acc[4][4];
    for (int i = 0; i < 4; ++i)
        for (int j = 0; j < 4; ++j) acc[i][j] = f32x4{0.f, 0.f, 0.f, 0.f};

    for (int k0 = 0; k0 < FDIM; k0 += 64) {
        for (int it = 0; it < 4; ++it) {
            int chunk = it * 256 + tid;
            int row = chunk >> 3, c = chunk & 7;
            int gcol = c ^ (row & 7);
            int ga = off + mt * 128 + row;
            if (ga > N_TOK - 1) ga = N_TOK - 1;
            gload16(hb + (size_t)ga * FDIM + k0 + gcol * 8, as + chunk * 8);
            int gb = nt * 128 + row;
            gload16(B + (size_t)gb * FDIM + k0 + gcol * 8, bs + chunk * 8);
        }
        __syncthreads();
        for (int ks = 0; ks < 64; ks += 32) {
            bf16x8 af[4], bfr[4];
            for (int mi = 0; mi < 4; ++mi) {
                int m = wr * 64 + mi * 16 + l15;
                int cc = ((ks >> 3) + q) ^ (m & 7);
                af[mi] = *(const bf16x8*)(as + m * 64 + cc * 8);
            }
            for (int ni = 0; ni < 4; ++ni) {
                int n = wc * 64 + ni * 16 + l15;
                int cc = ((ks >> 3) + q) ^ (n & 7);
                bfr[ni] = *(const bf16x8*)(bs + n * 64 + cc * 8);
            }
            for (int mi = 0; mi < 4; ++mi)
                for (int ni = 0; ni < 4; ++ni)
                    acc[mi][ni] = __builtin_amdgcn_mfma_f32_16x16x32_bf16(
                        af[mi], bfr[ni], acc[mi][ni], 0, 0, 0);
        }
        __syncthreads();
    }
    float bcol[4];
    for (int ni = 0; ni < 4; ++ni) bcol[ni] = b2[e * DIM + nt * 128 + wc * 64 + ni * 16 + l15];
    for (int mi = 0; mi < 4; ++mi) {
        for (int r = 0; r < 4; ++r) {
            int mrow = mt * 128 + wr * 64 + mi * 16 + q * 4 + r;
            if (mrow >= cnt) continue;
            int tok = perm[off + mrow];
            float g = topval[tok] * scale;
            size_t base = (size_t)tok * DIM + nt * 128;
            for (int ni = 0; ni < 4; ++ni) {
                float v = acc[mi][ni][r] + bcol[ni];
                out[base + wc * 64 + ni * 16 + l15] = g * v;
            }
        }
    }
}

extern "C" void kernel_launch(void* const* d_in, const int* in_sizes, int n_in,
                              void* d_out, int out_size, void* d_ws, size_t ws_size,
                              hipStream_t stream) {
    const float* x  = (const float*)d_in[0];
    const float* Wg = (const float*)d_in[1];
    const float* W1 = (const float*)d_in[2];
    const float* b1 = (const float*)d_in[3];
    const float* W2 = (const float*)d_in[4];
    const float* b2 = (const float*)d_in[5];
    float* out = (float*)d_out;

    char* W = (char*)d_ws;
    int*   counts = (int*)W;               // 8 ints
    float* denom  = (float*)(W + 64);      // 8 floats
    int*   offs   = (int*)(W + 128);       // 9 ints
    int*   top1   = (int*)(W + 256);
    float* topval = (float*)(W + 256 + 65536);
    int*   pos    = (int*)(W + 256 + 131072);
    int*   perm   = (int*)(W + 256 + 196608);
    u16*   xg     = (u16*)(W + 262400);                     // N*D bf16 = 16 MB
    u16*   w1t    = xg  + (size_t)N_TOK * DIM;              // E*F*D bf16 = 16 MB
    u16*   w2t    = w1t + (size_t)NEXP * FDIM * DIM;        // E*D*F bf16 = 16 MB
    u16*   hb     = w2t + (size_t)NEXP * DIM * FDIM;        // N*F bf16 = 64 MB

    hipMemsetAsync(W, 0, 128, stream);  // counts + denom
    k_router<<<N_TOK / 32, 256, 0, stream>>>(x, Wg, top1, topval, pos, counts, denom);
    k_prefix<<<1, 1, 0, stream>>>(counts, offs);
    k_gather<<<N_TOK / 4, 256, 0, stream>>>(x, top1, pos, offs, perm, xg);
    k_transpose_cvt<<<dim3(FDIM / 32, DIM / 32, NEXP), 256, 0, stream>>>(W1, w1t, DIM, FDIM);
    k_transpose_cvt<<<dim3(DIM / 32, FDIM / 32, NEXP), 256, 0, stream>>>(W2, w2t, FDIM, DIM);
    k_ffn1<<<NEXP * 128 * 16, 256, 0, stream>>>(xg, w1t, b1, counts, offs, hb);
    k_ffn2<<<NEXP * 128 * 4, 256, 0, stream>>>(hb, w2t, b2, counts, offs, perm, topval, denom, out);
}

// Round 3
// 322.620 us; speedup vs baseline: 1.4433x; 1.1157x over previous
//
#include <hip/hip_runtime.h>
#include <hip/hip_bf16.h>

// SwitchMoE: N=16384 tokens, D=512, F=2048, E=8, top-1 routing, capacity=N.
// Sparse formulation: each token goes through exactly ONE expert's FFN.
// Router fp32 (argmax safety); FFN bf16 MFMA 16x16x32, fp32 accumulate.
//
// R3: the whole pipeline was workgroup-dispatch-bound (~7 ns/block x 41K
// blocks ~= 290us). ffn1 was 16384 blocks with 87% early-exits at 6.9 ns/block.
// Fix: device-built m-tile table (<=135 entries) -> ffn1 grid 2176, ffn2 544;
// transpose 64x64x2-per-block -> 2x1024; gather 32 tok/block -> 512.
//
// ws layout: counts/denom/offs/nmt/tiletab | top1/topval/pos/perm |
//   xg bf16[N][D] | w1t bf16[E][F][D] | w2t bf16[E][D][F] | hb bf16[N][F]

typedef unsigned short u16;
typedef unsigned int u32;
typedef __bf16 bf16x8 __attribute__((ext_vector_type(8)));
typedef u16 u16x8 __attribute__((ext_vector_type(8)));
typedef float f32x4 __attribute__((ext_vector_type(4)));

#define N_TOK 16384
#define DIM   512
#define FDIM  2048
#define NEXP  8

__device__ inline u16 f2bf(float f) {
    u32 u = __float_as_uint(f);
    u = (u + 0x7FFF + ((u >> 16) & 1)) >> 16;  // RNE
    return (u16)u;
}

__device__ inline void gload16(const u16* g, u16* l) {
    __builtin_amdgcn_global_load_lds(
        (const __attribute__((address_space(1))) u32*)g,
        (__attribute__((address_space(3))) u32*)l, 16, 0, 0);
}

// ---------------- Router: wave-per-token fp32 logits + argmax + block-agg ----
__global__ __launch_bounds__(256) void k_router(
    const float* __restrict__ x, const float* __restrict__ Wg,
    int* __restrict__ top1, float* __restrict__ topval,
    int* __restrict__ pos, int* __restrict__ counts, float* __restrict__ denom) {
    __shared__ float4 wgs4[NEXP * 128];   // 16 KB
    __shared__ int   lcnt[NEXP];
    __shared__ float lden[NEXP];
    __shared__ int   lbase[NEXP];
    __shared__ int   ltok_e[32];
    __shared__ int   ltok_r[32];
    const int tid = threadIdx.x;
    const int lane = tid & 63, wv = tid >> 6;
    for (int i = tid; i < NEXP * 128; i += 256) wgs4[i] = ((const float4*)Wg)[i];
    if (tid < NEXP) { lcnt[tid] = 0; lden[tid] = 0.f; }
    __syncthreads();
    const int tok0 = blockIdx.x * 32;
    for (int tt = 0; tt < 8; ++tt) {
        const int tloc = wv * 8 + tt;
        const int n = tok0 + tloc;
        const float4* xr = (const float4*)(x + (size_t)n * DIM);
        float4 a = xr[lane], b = xr[64 + lane];
        float p[NEXP];
#pragma unroll
        for (int e = 0; e < NEXP; ++e) {
            float4 wa = wgs4[e * 128 + lane], wb = wgs4[e * 128 + 64 + lane];
            p[e] = a.x * wa.x + a.y * wa.y + a.z * wa.z + a.w * wa.w
                 + b.x * wb.x + b.y * wb.y + b.z * wb.z + b.w * wb.w;
        }
#pragma unroll
        for (int e = 0; e < NEXP; ++e)
#pragma unroll
            for (int m = 32; m >= 1; m >>= 1)
                p[e] += __shfl_xor(p[e], m, 64);
        if (lane == 0) {
            float best = p[0]; int be = 0;
#pragma unroll
            for (int e = 1; e < NEXP; ++e)
                if (p[e] > best) { best = p[e]; be = e; }  // strict >: first idx (jnp.argmax)
            top1[n] = be;
            topval[n] = best;
            ltok_e[tloc] = be;
            ltok_r[tloc] = atomicAdd(&lcnt[be], 1);
            atomicAdd(&lden[be], best);
        }
    }
    __syncthreads();
    if (tid < NEXP) {
        int c = lcnt[tid];
        lbase[tid] = c ? atomicAdd(&counts[tid], c) : 0;
        float dsum = lden[tid];
        if (dsum != 0.f) atomicAdd(&denom[tid], dsum);
    }
    __syncthreads();
    if (tid < 32) {
        int n = tok0 + tid;
        pos[n] = lbase[ltok_e[tid]] + ltok_r[tid];
    }
}

// ---------------- Plan: offsets + compact m-tile table (<=135 entries) -------
__global__ void k_plan(const int* __restrict__ counts, int* __restrict__ offs,
                       int* __restrict__ tile_e, int* __restrict__ tile_row,
                       int* __restrict__ tile_rows, int* __restrict__ nmt) {
    if (threadIdx.x == 0) {
        int s = 0, t = 0;
        for (int e = 0; e < NEXP; ++e) {
            offs[e] = s;
            int c = counts[e];
            for (int r = 0; r < c; r += 128) {
                tile_e[t] = e;
                tile_row[t] = s + r;
                tile_rows[t] = (c - r < 128) ? (c - r) : 128;
                ++t;
            }
            s += c;
        }
        offs[NEXP] = s;
        nmt[0] = t;
    }
}

// ---------------- Gather: 32 tokens/block -> expert-contiguous bf16 ----------
__global__ __launch_bounds__(256) void k_gather(
    const float* __restrict__ x, const int* __restrict__ top1,
    const int* __restrict__ pos, const int* __restrict__ offs,
    int* __restrict__ perm, u16* __restrict__ xg) {
    const int wid = threadIdx.x >> 6, lane = threadIdx.x & 63;
    const int n0 = blockIdx.x * 32 + wid * 8;
    for (int tt = 0; tt < 8; ++tt) {
        const int n = n0 + tt;
        const int e = top1[n];
        const int dst = offs[e] + pos[n];
        if (lane == 0) perm[dst] = n;
        const float4* src = (const float4*)(x + (size_t)n * DIM);
        float4 a = src[lane * 2], b = src[lane * 2 + 1];
        u16x8 v;
        v[0] = f2bf(a.x); v[1] = f2bf(a.y); v[2] = f2bf(a.z); v[3] = f2bf(a.w);
        v[4] = f2bf(b.x); v[5] = f2bf(b.y); v[6] = f2bf(b.z); v[7] = f2bf(b.w);
        *(u16x8*)(xg + (size_t)dst * DIM + lane * 8) = v;
    }
}

// ---------------- Transpose+cvt: dst[c*R+r] = bf16(src[r*C+c]), 2x 64x64/blk -
__global__ __launch_bounds__(256) void k_transpose_cvt(
    const float* __restrict__ src, u16* __restrict__ dst, int R, int C) {
    __shared__ float tile[64][65];  // 16.6 KB
    const int tilesPerMat = (R / 64) * (C / 64);
    const int cT = C / 64;
    for (int it = 0; it < 2; ++it) {
        const int gt = blockIdx.x * 2 + it;
        const int e = gt / tilesPerMat;
        const int rem = gt % tilesPerMat;
        const int r0 = (rem / cT) * 64, c0 = (rem % cT) * 64;
        const float* s = src + (size_t)e * R * C;
        u16* d = dst + (size_t)e * R * C;
        __syncthreads();
        const int lr = threadIdx.x >> 4;
        const int lc = (threadIdx.x & 15) * 4;
        for (int i = 0; i < 4; ++i) {
            int r = lr + i * 16;
            float4 v = *(const float4*)(s + (size_t)(r0 + r) * C + c0 + lc);
            tile[r][lc] = v.x; tile[r][lc + 1] = v.y;
            tile[r][lc + 2] = v.z; tile[r][lc + 3] = v.w;
        }
        __syncthreads();
        const int oc = threadIdx.x >> 3;
        const int orr = (threadIdx.x & 7) * 8;
        for (int p = 0; p < 2; ++p) {
            int c = oc + p * 32;
            u16x8 v;
            for (int j = 0; j < 8; ++j) v[j] = f2bf(tile[orr + j][c]);
            *(u16x8*)(d + (size_t)(c0 + c) * R + r0 + orr) = v;
        }
    }
}

// ---------------- Grouped GEMM1: hb = relu(xg @ W1 + b1) ---------------------
// grid (16 n-tiles, 136 m-slots); tile table gives (e, row0, rows).
__global__ __launch_bounds__(256) void k_ffn1(
    const u16* __restrict__ xg, const u16* __restrict__ w1t,
    const float* __restrict__ b1,
    const int* __restrict__ tile_e, const int* __restrict__ tile_row,
    const int* __restrict__ tile_rows, const int* __restrict__ nmt,
    u16* __restrict__ hb) {
    const int ms = blockIdx.y;
    if (ms >= nmt[0]) return;
    const int nt = blockIdx.x;
    const int e = tile_e[ms];
    const int row0 = tile_row[ms];
    const int rows = tile_rows[ms];
    __shared__ u16 as[128 * 64];
    __shared__ u16 bs[128 * 64];
    const u16* B = w1t + (size_t)e * FDIM * DIM;
    const int tid = threadIdx.x;
    const int lane = tid & 63, wid = tid >> 6;
    const int wr = wid >> 1, wc = wid & 1;
    const int q = lane >> 4, l15 = lane & 15;
    f32x4 acc[4][4];
    for (int i = 0; i < 4; ++i)
        for (int j = 0; j < 4; ++j) acc[i][j] = f32x4{0.f, 0.f, 0.f, 0.f};

    for (int k0 = 0; k0 < DIM; k0 += 64) {
        for (int it = 0; it < 4; ++it) {
            int chunk = it * 256 + tid;
            int row = chunk >> 3, c = chunk & 7;
            int gcol = c ^ (row & 7);  // XOR swizzle: conflict-free ds_read_b128
            int rr = row < rows ? row : rows - 1;
            gload16(xg + (size_t)(row0 + rr) * DIM + k0 + gcol * 8, as + chunk * 8);
            int gb = nt * 128 + row;
            gload16(B + (size_t)gb * DIM + k0 + gcol * 8, bs + chunk * 8);
        }
        __syncthreads();
        for (int ks = 0; ks < 64; ks += 32) {
            bf16x8 af[4], bfr[4];
            for (int mi = 0; mi < 4; ++mi) {
                int m = wr * 64 + mi * 16 + l15;
                int cc = ((ks >> 3) + q) ^ (m & 7);
                af[mi] = *(const bf16x8*)(as + m * 64 + cc * 8);
            }
            for (int ni = 0; ni < 4; ++ni) {
                int n = wc * 64 + ni * 16 + l15;
                int cc = ((ks >> 3) + q) ^ (n & 7);
                bfr[ni] = *(const bf16x8*)(bs + n * 64 + cc * 8);
            }
            for (int mi = 0; mi < 4; ++mi)
                for (int ni = 0; ni < 4; ++ni)
                    acc[mi][ni] = __builtin_amdgcn_mfma_f32_16x16x32_bf16(
                        af[mi], bfr[ni], acc[mi][ni], 0, 0, 0);
        }
        __syncthreads();
    }
    const float* b1e = b1 + e * FDIM + nt * 128;
    float bcol[4];
    for (int ni = 0; ni < 4; ++ni) bcol[ni] = b1e[wc * 64 + ni * 16 + l15];
    for (int mi = 0; mi < 4; ++mi) {
        for (int r = 0; r < 4; ++r) {
            int mrow = wr * 64 + mi * 16 + q * 4 + r;
            if (mrow >= rows) continue;
            size_t base = (size_t)(row0 + mrow) * FDIM + nt * 128;
            for (int ni = 0; ni < 4; ++ni) {
                float v = acc[mi][ni][r] + bcol[ni];
                v = v > 0.f ? v : 0.f;
                hb[base + wc * 64 + ni * 16 + l15] = f2bf(v);
            }
        }
    }
}

// ---------------- Grouped GEMM2: out[tok] = gate * (hb @ W2 + b2) ------------
__global__ __launch_bounds__(256) void k_ffn2(
    const u16* __restrict__ hb, const u16* __restrict__ w2t,
    const float* __restrict__ b2,
    const int* __restrict__ tile_e, const int* __restrict__ tile_row,
    const int* __restrict__ tile_rows, const int* __restrict__ nmt,
    const int* __restrict__ perm, const float* __restrict__ topval,
    const float* __restrict__ denom, float* __restrict__ out) {
    const int ms = blockIdx.y;
    if (ms >= nmt[0]) return;
    const int nt = blockIdx.x;
    const int e = tile_e[ms];
    const int row0 = tile_row[ms];
    const int rows = tile_rows[ms];
    const float scale = 16384.0f / (denom[e] + 1e-6f);
    __shared__ u16 as[128 * 64];
    __shared__ u16 bs[128 * 64];
    const u16* B = w2t + (size_t)e * DIM * FDIM;
    const int tid = threadIdx.x;
    const int lane = tid & 63, wid = tid >> 6;
    const int wr = wid >> 1, wc = wid & 1;
    const int q = lane >> 4, l15 = lane & 15;
    f32x4 acc[4][4];
    for (int i = 0; i < 4; ++i)
        for (int j = 0; j < 4; ++j) acc[i][j] = f32x4{0.f, 0.f, 0.f, 0.f};

    for (int k0 = 0; k0 < FDIM; k0 += 64) {
        for (int it = 0; it < 4; ++it) {
            int chunk = it * 256 + tid;
            int row = chunk >> 3, c = chunk & 7;
            int gcol = c ^ (row & 7);
            int rr = row < rows ? row : rows - 1;
            gload16(hb + (size_t)(row0 + rr) * FDIM + k0 + gcol * 8, as + chunk * 8);
            int gb = nt * 128 + row;
            gload16(B + (size_t)gb * FDIM + k0 + gcol * 8, bs + chunk * 8);
        }
        __syncthreads();
        for (int ks = 0; ks < 64; ks += 32) {
            bf16x8 af[4], bfr[4];
            for (int mi = 0; mi < 4; ++mi) {
                int m = wr * 64 + mi * 16 + l15;
                int cc = ((ks >> 3) + q) ^ (m & 7);
                af[mi] = *(const bf16x8*)(as + m * 64 + cc * 8);
            }
            for (int ni = 0; ni < 4; ++ni) {
                int n = wc * 64 + ni * 16 + l15;
                int cc = ((ks >> 3) + q) ^ (n & 7);
                bfr[ni] = *(const bf16x8*)(bs + n * 64 + cc * 8);
            }
            for (int mi = 0; mi < 4; ++mi)
                for (int ni = 0; ni < 4; ++ni)
                    acc[mi][ni] = __builtin_amdgcn_mfma_f32_16x16x32_bf16(
                        af[mi], bfr[ni], acc[mi][ni], 0, 0, 0);
        }
        __syncthreads();
    }
    float bcol[4];
    for (int ni = 0; ni < 4; ++ni) bcol[ni] = b2[e * DIM + nt * 128 + wc * 64 + ni * 16 + l15];
    for (int mi = 0; mi < 4; ++mi) {
        for (int r = 0; r < 4; ++r) {
            int mrow = wr * 64 + mi * 16 + q * 4 + r;
            if (mrow >= rows) continue;
            int tok = perm[row0 + mrow];
            float g = topval[tok] * scale;
            size_t base = (size_t)tok * DIM + nt * 128;
            for (int ni = 0; ni < 4; ++ni) {
                float v = acc[mi][ni][r] + bcol[ni];
                out[base + wc * 64 + ni * 16 + l15] = g * v;
            }
        }
    }
}

extern "C" void kernel_launch(void* const* d_in, const int* in_sizes, int n_in,
                              void* d_out, int out_size, void* d_ws, size_t ws_size,
                              hipStream_t stream) {
    const float* x  = (const float*)d_in[0];
    const float* Wg = (const float*)d_in[1];
    const float* W1 = (const float*)d_in[2];
    const float* b1 = (const float*)d_in[3];
    const float* W2 = (const float*)d_in[4];
    const float* b2 = (const float*)d_in[5];
    float* out = (float*)d_out;

    char* W = (char*)d_ws;
    int*   counts    = (int*)W;               // 8 ints
    float* denom     = (float*)(W + 64);      // 8 floats
    int*   offs      = (int*)(W + 128);       // 9 ints
    int*   nmt       = (int*)(W + 192);       // 1 int
    int*   tile_e    = (int*)(W + 256);       // <=136 ints
    int*   tile_row  = (int*)(W + 1280);
    int*   tile_rows = (int*)(W + 2304);
    int*   top1      = (int*)(W + 4096);
    float* topval    = (float*)(W + 4096 + 65536);
    int*   pos       = (int*)(W + 4096 + 131072);
    int*   perm      = (int*)(W + 4096 + 196608);
    u16*   xg        = (u16*)(W + 266240);                  // N*D bf16 = 16 MB
    u16*   w1t       = xg  + (size_t)N_TOK * DIM;           // E*F*D bf16 = 16 MB
    u16*   w2t       = w1t + (size_t)NEXP * FDIM * DIM;     // E*D*F bf16 = 16 MB
    u16*   hb        = w2t + (size_t)NEXP * DIM * FDIM;     // N*F bf16 = 64 MB

    hipMemsetAsync(W, 0, 128, stream);  // counts + denom
    k_router<<<N_TOK / 32, 256, 0, stream>>>(x, Wg, top1, topval, pos, counts, denom);
    k_plan<<<1, 64, 0, stream>>>(counts, offs, tile_e, tile_row, tile_rows, nmt);
    k_gather<<<N_TOK / 32, 256, 0, stream>>>(x, top1, pos, offs, perm, xg);
    k_transpose_cvt<<<NEXP * (DIM / 64) * (FDIM / 64) / 2, 256, 0, stream>>>(W1, w1t, DIM, FDIM);
    k_transpose_cvt<<<NEXP * (FDIM / 64) * (DIM / 64) / 2, 256, 0, stream>>>(W2, w2t, FDIM, DIM);
    k_ffn1<<<dim3(16, 136), 256, 0, stream>>>(xg, w1t, b1, tile_e, tile_row, tile_rows, nmt, hb);
    k_ffn2<<<dim3(4, 136), 256, 0, stream>>>(hb, w2t, b2, tile_e, tile_row, tile_rows, nmt,
                                             perm, topval, denom, out);
}

// Round 4
// 293.077 us; speedup vs baseline: 1.5888x; 1.1008x over previous
//
#include <hip/hip_runtime.h>
#include <hip/hip_bf16.h>

// SwitchMoE: N=16384 tokens, D=512, F=2048, E=8, top-1 routing, capacity=N.
// Sparse: each token through exactly ONE expert FFN. Router fp32; FFN bf16
// MFMA 16x16x32 fp32-acc.
//
// R4: ffn2 was staging-rate-bound at 9 B/cyc/CU (2.1 resident blocks/CU,
// grid 544). -> BN=64, grid 1088 (4.25 blocks/CU) + XCD swizzle so A-sharing
// blocks land on one XCD L2. k_plan folded into consumers; transposes merged.
//
// ws: counts/denom | top1/topval/pos/perm | xg bf16[N][D] | w1t bf16[E][F][D]
//     | w2t bf16[E][D][F] | hb bf16[N][F]

typedef unsigned short u16;
typedef unsigned int u32;
typedef __bf16 bf16x8 __attribute__((ext_vector_type(8)));
typedef u16 u16x8 __attribute__((ext_vector_type(8)));
typedef float f32x4 __attribute__((ext_vector_type(4)));

#define N_TOK 16384
#define DIM   512
#define FDIM  2048
#define NEXP  8

__device__ inline u16 f2bf(float f) {
    u32 u = __float_as_uint(f);
    u = (u + 0x7FFF + ((u >> 16) & 1)) >> 16;  // RNE
    return (u16)u;
}

__device__ inline void gload16(const u16* g, u16* l) {
    __builtin_amdgcn_global_load_lds(
        (const __attribute__((address_space(1))) u32*)g,
        (__attribute__((address_space(3))) u32*)l, 16, 0, 0);
}

// Walk counts -> (expert, row0, rows) for 128-row m-slot `ms`. <=136 slots.
__device__ inline bool decode_ms(const int* __restrict__ counts, int ms,
                                 int& e, int& row0, int& rows) {
    int t = 0, s = 0;
    for (int ee = 0; ee < NEXP; ++ee) {
        int c = counts[ee];
        int ntile = (c + 127) >> 7;
        if (ms < t + ntile) {
            int r = (ms - t) << 7;
            e = ee; row0 = s + r; rows = (c - r < 128) ? (c - r) : 128;
            return true;
        }
        t += ntile; s += c;
    }
    return false;
}

// ---------------- Router: wave-per-token fp32 logits + argmax + block-agg ----
__global__ __launch_bounds__(256) void k_router(
    const float* __restrict__ x, const float* __restrict__ Wg,
    int* __restrict__ top1, float* __restrict__ topval,
    int* __restrict__ pos, int* __restrict__ counts, float* __restrict__ denom) {
    __shared__ float4 wgs4[NEXP * 128];   // 16 KB
    __shared__ int   lcnt[NEXP];
    __shared__ float lden[NEXP];
    __shared__ int   lbase[NEXP];
    __shared__ int   ltok_e[32];
    __shared__ int   ltok_r[32];
    const int tid = threadIdx.x;
    const int lane = tid & 63, wv = tid >> 6;
    for (int i = tid; i < NEXP * 128; i += 256) wgs4[i] = ((const float4*)Wg)[i];
    if (tid < NEXP) { lcnt[tid] = 0; lden[tid] = 0.f; }
    __syncthreads();
    const int tok0 = blockIdx.x * 32;
    for (int tt = 0; tt < 8; ++tt) {
        const int tloc = wv * 8 + tt;
        const int n = tok0 + tloc;
        const float4* xr = (const float4*)(x + (size_t)n * DIM);
        float4 a = xr[lane], b = xr[64 + lane];
        float p[NEXP];
#pragma unroll
        for (int e = 0; e < NEXP; ++e) {
            float4 wa = wgs4[e * 128 + lane], wb = wgs4[e * 128 + 64 + lane];
            p[e] = a.x * wa.x + a.y * wa.y + a.z * wa.z + a.w * wa.w
                 + b.x * wb.x + b.y * wb.y + b.z * wb.z + b.w * wb.w;
        }
#pragma unroll
        for (int e = 0; e < NEXP; ++e)
#pragma unroll
            for (int m = 32; m >= 1; m >>= 1)
                p[e] += __shfl_xor(p[e], m, 64);
        if (lane == 0) {
            float best = p[0]; int be = 0;
#pragma unroll
            for (int e = 1; e < NEXP; ++e)
                if (p[e] > best) { best = p[e]; be = e; }  // strict >: first idx (jnp.argmax)
            top1[n] = be;
            topval[n] = best;
            ltok_e[tloc] = be;
            ltok_r[tloc] = atomicAdd(&lcnt[be], 1);
            atomicAdd(&lden[be], best);
        }
    }
    __syncthreads();
    if (tid < NEXP) {
        int c = lcnt[tid];
        lbase[tid] = c ? atomicAdd(&counts[tid], c) : 0;
        float dsum = lden[tid];
        if (dsum != 0.f) atomicAdd(&denom[tid], dsum);
    }
    __syncthreads();
    if (tid < 32) {
        int n = tok0 + tid;
        pos[n] = lbase[ltok_e[tid]] + ltok_r[tid];
    }
}

// ---------------- Gather: 32 tokens/block -> expert-contiguous bf16 ----------
__global__ __launch_bounds__(256) void k_gather(
    const float* __restrict__ x, const int* __restrict__ top1,
    const int* __restrict__ pos, const int* __restrict__ counts,
    int* __restrict__ perm, u16* __restrict__ xg) {
    __shared__ int soffs[NEXP];
    if (threadIdx.x == 0) {
        int s = 0;
        for (int e = 0; e < NEXP; ++e) { soffs[e] = s; s += counts[e]; }
    }
    __syncthreads();
    const int wid = threadIdx.x >> 6, lane = threadIdx.x & 63;
    const int n0 = blockIdx.x * 32 + wid * 8;
    for (int tt = 0; tt < 8; ++tt) {
        const int n = n0 + tt;
        const int e = top1[n];
        const int dst = soffs[e] + pos[n];
        if (lane == 0) perm[dst] = n;
        const float4* src = (const float4*)(x + (size_t)n * DIM);
        float4 a = src[lane * 2], b = src[lane * 2 + 1];
        u16x8 v;
        v[0] = f2bf(a.x); v[1] = f2bf(a.y); v[2] = f2bf(a.z); v[3] = f2bf(a.w);
        v[4] = f2bf(b.x); v[5] = f2bf(b.y); v[6] = f2bf(b.z); v[7] = f2bf(b.w);
        *(u16x8*)(xg + (size_t)dst * DIM + lane * 8) = v;
    }
}

// ---------------- Both weight transposes in one kernel (2x 64x64 tiles/blk) --
// dst[c*R + r] = bf16(src[r*C + c]); 256 tiles per expert-matrix either way.
__global__ __launch_bounds__(256) void k_wt(
    const float* __restrict__ W1, const float* __restrict__ W2,
    u16* __restrict__ w1t, u16* __restrict__ w2t) {
    __shared__ float tile[64][65];  // 16.6 KB
    const int bid = blockIdx.x;
    const int isW2 = bid >= 1024;
    const float* srcM = isW2 ? W2 : W1;
    u16* dstM = isW2 ? w2t : w1t;
    const int R = isW2 ? FDIM : DIM;
    const int C = isW2 ? DIM : FDIM;
    const int cT = C / 64;
    const int lb = isW2 ? bid - 1024 : bid;
    for (int it = 0; it < 2; ++it) {
        const int gt = lb * 2 + it;
        const int e = gt >> 8;            // 256 tiles per matrix
        const int rem = gt & 255;
        const int r0 = (rem / cT) * 64, c0 = (rem % cT) * 64;
        const float* s = srcM + (size_t)e * R * C;
        u16* d = dstM + (size_t)e * R * C;
        __syncthreads();
        const int lr = threadIdx.x >> 4;
        const int lc = (threadIdx.x & 15) * 4;
        for (int i = 0; i < 4; ++i) {
            int r = lr + i * 16;
            float4 v = *(const float4*)(s + (size_t)(r0 + r) * C + c0 + lc);
            tile[r][lc] = v.x; tile[r][lc + 1] = v.y;
            tile[r][lc + 2] = v.z; tile[r][lc + 3] = v.w;
        }
        __syncthreads();
        const int oc = threadIdx.x >> 3;
        const int orr = (threadIdx.x & 7) * 8;
        for (int p = 0; p < 2; ++p) {
            int c = oc + p * 32;
            u16x8 v;
            for (int j = 0; j < 8; ++j) v[j] = f2bf(tile[orr + j][c]);
            *(u16x8*)(d + (size_t)(c0 + c) * R + r0 + orr) = v;
        }
    }
}

// ---------------- Grouped GEMM1: hb = relu(xg @ W1 + b1), 128x128x64 ---------
// 1D grid 2176 = 8 xcd-groups x 16 nt x 17; same-ms blocks share an XCD.
__global__ __launch_bounds__(256) void k_ffn1(
    const u16* __restrict__ xg, const u16* __restrict__ w1t,
    const float* __restrict__ b1, const int* __restrict__ counts,
    u16* __restrict__ hb) {
    const int b = blockIdx.x;
    const int cx = b & 7;
    const int t = b >> 3;
    const int nt = t & 15;
    const int j = t >> 4;           // 0..16
    const int ms = cx + 8 * j;      // 0..135
    int e, row0, rows;
    if (!decode_ms(counts, ms, e, row0, rows)) return;
    __shared__ u16 as[128 * 64];
    __shared__ u16 bs[128 * 64];
    const u16* B = w1t + (size_t)e * FDIM * DIM;
    const int tid = threadIdx.x;
    const int lane = tid & 63, wid = tid >> 6;
    const int wr = wid >> 1, wc = wid & 1;
    const int q = lane >> 4, l15 = lane & 15;
    f32x4 acc[4][4];
    for (int i = 0; i < 4; ++i)
        for (int jj = 0; jj < 4; ++jj) acc[i][jj] = f32x4{0.f, 0.f, 0.f, 0.f};

    for (int k0 = 0; k0 < DIM; k0 += 64) {
        for (int it = 0; it < 4; ++it) {
            int chunk = it * 256 + tid;
            int row = chunk >> 3, c = chunk & 7;
            int gcol = c ^ (row & 7);  // XOR swizzle: conflict-free ds_read_b128
            int rr = row < rows ? row : rows - 1;
            gload16(xg + (size_t)(row0 + rr) * DIM + k0 + gcol * 8, as + chunk * 8);
            int gb = nt * 128 + row;
            gload16(B + (size_t)gb * DIM + k0 + gcol * 8, bs + chunk * 8);
        }
        __syncthreads();
        for (int ks = 0; ks < 64; ks += 32) {
            bf16x8 af[4], bfr[4];
            for (int mi = 0; mi < 4; ++mi) {
                int m = wr * 64 + mi * 16 + l15;
                int cc = ((ks >> 3) + q) ^ (m & 7);
                af[mi] = *(const bf16x8*)(as + m * 64 + cc * 8);
            }
            for (int ni = 0; ni < 4; ++ni) {
                int n = wc * 64 + ni * 16 + l15;
                int cc = ((ks >> 3) + q) ^ (n & 7);
                bfr[ni] = *(const bf16x8*)(bs + n * 64 + cc * 8);
            }
            for (int mi = 0; mi < 4; ++mi)
                for (int ni = 0; ni < 4; ++ni)
                    acc[mi][ni] = __builtin_amdgcn_mfma_f32_16x16x32_bf16(
                        af[mi], bfr[ni], acc[mi][ni], 0, 0, 0);
        }
        __syncthreads();
    }
    const float* b1e = b1 + e * FDIM + nt * 128;
    float bcol[4];
    for (int ni = 0; ni < 4; ++ni) bcol[ni] = b1e[wc * 64 + ni * 16 + l15];
    for (int mi = 0; mi < 4; ++mi) {
        for (int r = 0; r < 4; ++r) {
            int mrow = wr * 64 + mi * 16 + q * 4 + r;
            if (mrow >= rows) continue;
            size_t base = (size_t)(row0 + mrow) * FDIM + nt * 128;
            for (int ni = 0; ni < 4; ++ni) {
                float v = acc[mi][ni][r] + bcol[ni];
                v = v > 0.f ? v : 0.f;
                hb[base + wc * 64 + ni * 16 + l15] = f2bf(v);
            }
        }
    }
}

// ---------------- Grouped GEMM2: out[tok] = gate*(hb @ W2 + b2), 128x64x64 ---
// 1D grid 1088 = 8 xcd-groups x 8 nt x 17; 4 waves of 32rows x 64cols.
__global__ __launch_bounds__(256) void k_ffn2(
    const u16* __restrict__ hb, const u16* __restrict__ w2t,
    const float* __restrict__ b2, const int* __restrict__ counts,
    const int* __restrict__ perm, const float* __restrict__ topval,
    const float* __restrict__ denom, float* __restrict__ out) {
    const int b = blockIdx.x;
    const int cx = b & 7;
    const int t = b >> 3;
    const int nt = t & 7;
    const int j = t >> 3;           // 0..16
    const int ms = cx + 8 * j;      // 0..135
    int e, row0, rows;
    if (!decode_ms(counts, ms, e, row0, rows)) return;
    const float scale = 16384.0f / (denom[e] + 1e-6f);
    __shared__ u16 as[128 * 64];    // 16 KB
    __shared__ u16 bs[64 * 64];     // 8 KB
    const u16* B = w2t + (size_t)e * DIM * FDIM + (size_t)(nt * 64) * FDIM;
    const int tid = threadIdx.x;
    const int lane = tid & 63, w = tid >> 6;
    const int q = lane >> 4, l15 = lane & 15;
    f32x4 acc[2][4];
    for (int i = 0; i < 2; ++i)
        for (int jj = 0; jj < 4; ++jj) acc[i][jj] = f32x4{0.f, 0.f, 0.f, 0.f};

    for (int k0 = 0; k0 < FDIM; k0 += 64) {
        for (int it = 0; it < 6; ++it) {
            if (it < 4) {
                int chunk = it * 256 + tid;
                int row = chunk >> 3, c = chunk & 7;
                int gcol = c ^ (row & 7);
                int rr = row < rows ? row : rows - 1;
                gload16(hb + (size_t)(row0 + rr) * FDIM + k0 + gcol * 8, as + chunk * 8);
            } else {
                int chunk = (it - 4) * 256 + tid;
                int row = chunk >> 3, c = chunk & 7;
                int gcol = c ^ (row & 7);
                gload16(B + (size_t)row * FDIM + k0 + gcol * 8, bs + chunk * 8);
            }
        }
        __syncthreads();
        for (int ks = 0; ks < 64; ks += 32) {
            bf16x8 af[2], bfr[4];
            for (int mi = 0; mi < 2; ++mi) {
                int m = w * 32 + mi * 16 + l15;
                int cc = ((ks >> 3) + q) ^ (m & 7);
                af[mi] = *(const bf16x8*)(as + m * 64 + cc * 8);
            }
            for (int ni = 0; ni < 4; ++ni) {
                int n = ni * 16 + l15;
                int cc = ((ks >> 3) + q) ^ (n & 7);
                bfr[ni] = *(const bf16x8*)(bs + n * 64 + cc * 8);
            }
            for (int mi = 0; mi < 2; ++mi)
                for (int ni = 0; ni < 4; ++ni)
                    acc[mi][ni] = __builtin_amdgcn_mfma_f32_16x16x32_bf16(
                        af[mi], bfr[ni], acc[mi][ni], 0, 0, 0);
        }
        __syncthreads();
    }
    float bcol[4];
    for (int ni = 0; ni < 4; ++ni) bcol[ni] = b2[e * DIM + nt * 64 + ni * 16 + l15];
    for (int mi = 0; mi < 2; ++mi) {
        for (int r = 0; r < 4; ++r) {
            int mrow = w * 32 + mi * 16 + q * 4 + r;
            if (mrow >= rows) continue;
            int tok = perm[row0 + mrow];
            float g = topval[tok] * scale;
            size_t base = (size_t)tok * DIM + nt * 64;
            for (int ni = 0; ni < 4; ++ni) {
                float v = acc[mi][ni][r] + bcol[ni];
                out[base + ni * 16 + l15] = g * v;
            }
        }
    }
}

extern "C" void kernel_launch(void* const* d_in, const int* in_sizes, int n_in,
                              void* d_out, int out_size, void* d_ws, size_t ws_size,
                              hipStream_t stream) {
    const float* x  = (const float*)d_in[0];
    const float* Wg = (const float*)d_in[1];
    const float* W1 = (const float*)d_in[2];
    const float* b1 = (const float*)d_in[3];
    const float* W2 = (const float*)d_in[4];
    const float* b2 = (const float*)d_in[5];
    float* out = (float*)d_out;

    char* W = (char*)d_ws;
    int*   counts = (int*)W;                // 8 ints
    float* denom  = (float*)(W + 64);       // 8 floats
    int*   top1   = (int*)(W + 4096);
    float* topval = (float*)(W + 4096 + 65536);
    int*   pos    = (int*)(W + 4096 + 131072);
    int*   perm   = (int*)(W + 4096 + 196608);
    u16*   xg     = (u16*)(W + 266240);                  // N*D bf16 = 16 MB
    u16*   w1t    = xg  + (size_t)N_TOK * DIM;           // E*F*D bf16 = 16 MB
    u16*   w2t    = w1t + (size_t)NEXP * FDIM * DIM;     // E*D*F bf16 = 16 MB
    u16*   hb     = w2t + (size_t)NEXP * DIM * FDIM;     // N*F bf16 = 64 MB

    hipMemsetAsync(W, 0, 128, stream);  // counts + denom
    k_router<<<N_TOK / 32, 256, 0, stream>>>(x, Wg, top1, topval, pos, counts, denom);
    k_gather<<<N_TOK / 32, 256, 0, stream>>>(x, top1, pos, counts, perm, xg);
    k_wt<<<2048, 256, 0, stream>>>(W1, W2, w1t, w2t);
    k_ffn1<<<2176, 256, 0, stream>>>(xg, w1t, b1, counts, hb);
    k_ffn2<<<1088, 256, 0, stream>>>(hb, w2t, b2, counts, perm, topval, denom, out);
}